// Round 16
// baseline (3277.047 us; speedup 1.0000x reference)
//
#include <hip/hip_runtime.h>
#include <hip/hip_bf16.h>
#include <stdint.h>

#define NNODES 100000
#define DF 64
#define NEDGES 1600000
#define ND (NNODES * DF)     // 6,400,000
#define BKT 100              // targets per bucket
#define NBUCK 1000           // BKT*NBUCK == NNODES
#define CHUNK 400            // edges per wave in agg phase (4000*400 == NEDGES)
#define NCHUNK (NEDGES / CHUNK)   // 4000
#define NPW 25               // nodes per range (4000 ranges * 25 == NNODES)
#define NRANGE 4000
#define NJOBS (2 * NRANGE)   // 8000 projection jobs (Ps and Pt)
#define NBLK 1024            // 4 blocks/CU * 256 CUs — co-resident by launch_bounds

// ---------- helpers ----------
static __device__ __forceinline__ float bf2f(unsigned short u) {
    union { uint32_t i; float f; } c; c.i = ((uint32_t)u) << 16; return c.f;
}
static __device__ __forceinline__ unsigned short f2bf(float f) {
    union { __hip_bfloat16 b; unsigned short u; } c; c.b = __float2bfloat16(f); return c.u;
}
static __device__ __forceinline__ void unpack2(uint32_t u, float& lo, float& hi) {
    union { uint32_t i; float f; } a, b;
    a.i = u << 16; b.i = u & 0xFFFF0000u;
    lo = a.f; hi = b.f;
}

// ---------- software grid barrier (device-scope, generation-based) ----------
// All NBLK blocks co-resident (launch_bounds(256,4), grid == 4*256). Thread 0
// arrives via agent-scope fetch_add; last block resets cnt then bumps gen;
// others spin on gen with agent-scope acquire loads (coherent across XCDs).
static __device__ __forceinline__ void gridbar(int* cnt, int* gen) {
    __threadfence();
    __syncthreads();
    if (threadIdx.x == 0) {
        int g = __hip_atomic_load(gen, __ATOMIC_ACQUIRE, __HIP_MEMORY_SCOPE_AGENT);
        int a = __hip_atomic_fetch_add(cnt, 1, __ATOMIC_ACQ_REL, __HIP_MEMORY_SCOPE_AGENT);
        if (a == NBLK - 1) {
            __hip_atomic_store(cnt, 0, __ATOMIC_RELAXED, __HIP_MEMORY_SCOPE_AGENT);
            __hip_atomic_fetch_add(gen, 1, __ATOMIC_ACQ_REL, __HIP_MEMORY_SCOPE_AGENT);
        } else {
            while (__hip_atomic_load(gen, __ATOMIC_ACQUIRE, __HIP_MEMORY_SCOPE_AGENT) == g)
                __builtin_amdgcn_s_sleep(8);
        }
    }
    __syncthreads();
    __threadfence();
}

// dot of row (bf16 or fp32) with per-lane weight array (inlined; w stays in regs)
static __device__ __forceinline__ float dot64(const void* xv, size_t n, int bf,
                                              const float (&w)[64]) {
    float a0 = 0.f, a1 = 0.f, a2 = 0.f, a3 = 0.f;
    if (bf) {
        const uint4* xr = (const uint4*)((const unsigned short*)xv + n * DF);
        #pragma unroll
        for (int q = 0; q < 8; ++q) {
            uint4 v = xr[q];
            float x0,x1,x2,x3,x4,x5,x6,x7;
            unpack2(v.x, x0, x1); unpack2(v.y, x2, x3);
            unpack2(v.z, x4, x5); unpack2(v.w, x6, x7);
            a0 = fmaf(x0, w[8*q+0], a0); a1 = fmaf(x1, w[8*q+1], a1);
            a2 = fmaf(x2, w[8*q+2], a2); a3 = fmaf(x3, w[8*q+3], a3);
            a0 = fmaf(x4, w[8*q+4], a0); a1 = fmaf(x5, w[8*q+5], a1);
            a2 = fmaf(x6, w[8*q+6], a2); a3 = fmaf(x7, w[8*q+7], a3);
        }
    } else {
        const float4* xr = (const float4*)((const float*)xv + n * DF);
        #pragma unroll
        for (int q = 0; q < 16; ++q) {
            float4 v = xr[q];
            a0 = fmaf(v.x, w[4*q+0], a0); a1 = fmaf(v.y, w[4*q+1], a1);
            a2 = fmaf(v.z, w[4*q+2], a2); a3 = fmaf(v.w, w[4*q+3], a3);
        }
    }
    return (a0 + a1) + (a2 + a3);
}

// projection jobs: jid&1 selects Ps (no bias) / Pt (+b_msg); jid>>1 = node range
static __device__ __forceinline__ void m1_work(int jobBase, int jobCount,
                                               int slot, int slots, int bf, int lane,
                                               const void* xv, const float* WfMT,
                                               const float* prm,
                                               unsigned short* Ps, unsigned short* Pt) {
    for (int j = slot; j < jobCount; j += slots) {
        int jid = jobBase + j;
        int mtx = jid & 1;
        int r = jid >> 1;
        const float* WT = WfMT + (mtx ? 4096 : 0);
        float w[64];
        #pragma unroll
        for (int k = 0; k < 64; ++k) w[k] = WT[k * 64 + lane];
        float bias = mtx ? prm[lane] : 0.f;
        unsigned short* outp = mtx ? Pt : Ps;
        int n0 = r * NPW, n1 = n0 + NPW;
        for (int n = n0; n < n1; ++n) {
            float acc = dot64(xv, (size_t)n, bf, w);
            outp[(size_t)n * DF + lane] = f2bf(acc + bias);
        }
    }
}

__global__ __launch_bounds__(256, 4) void mega_k(
    const void* xv, const int* ei,
    const void* Wm, const void* bmv, const void* Wu, const void* buv,
    const void* gav, const void* bev,
    unsigned short* Ps, unsigned short* Pt, unsigned short* Msg,
    int* BktE, int* CsrSrc, int* Row,
    int* BktCnt, int* BktOff, int* BktCur,
    int* bar,                       // [0]=cnt, [1]=gen (zeroed per launch)
    float* WfMT, float* WfUT, float* prm,
    void* outv) {
    __shared__ int smem[3 * NBUCK + 8];   // 12 KB, reused per phase
    const int tid = threadIdx.x;
    const int blk = blockIdx.x;
    const int lane = tid & 63;
    const int wib = tid >> 6;
    int* cnt = bar;
    int* gen = bar + 1;

    // ---- local dtype detection (every block; same data -> same answer) ----
    if (tid == 0) { smem[3*NBUCK] = 0; smem[3*NBUCK + 1] = 0; }
    __syncthreads();
    {
        unsigned short s = ((const unsigned short*)xv)[tid * 2];
        unsigned short m = s & 0x7FFF;
        if (m < 0x0080 || (m >= 0x3000 && m <= 0x4200)) atomicAdd(&smem[3*NBUCK], 1);
        if (tid < 64 && ((const unsigned int*)ei)[tid * 2 + 1] != 0u)
            atomicAdd(&smem[3*NBUCK + 1], 1);
    }
    __syncthreads();
    const int bf  = (smem[3*NBUCK] >= 192) ? 1 : 0;
    const int i64 = (smem[3*NBUCK + 1] == 0) ? 1 : 0;
    __syncthreads();

    // ================= P0: bhist (blocks 0-255) + wconv (blocks 256-321) ==========
    if (blk < 256) {
        for (int i = tid; i < NBUCK; i += 256) smem[i] = 0;
        __syncthreads();
        for (int e = blk * 256 + tid; e < NEDGES; e += 65536) {
            int tgt = i64 ? ei[4*e + 2] : ei[2*e + 1];
            if ((unsigned)tgt < NNODES) atomicAdd(&smem[tgt / BKT], 1);
        }
        __syncthreads();
        for (int b = tid; b < NBUCK; b += 256)
            if (smem[b]) atomicAdd(BktCnt + b, smem[b]);
    } else if (blk < 322) {
        int i = (blk - 256) * 256 + tid;
        if (i < 16384) {
            const void* src = (i < 8192) ? Wm : Wu;
            float* dst = (i < 8192) ? WfMT : WfUT;
            int ii = i & 8191, j = ii >> 6, k = ii & 63;
            int si = (j & 63) * 128 + ((j >> 6) ? 64 : 0) + k;
            float v = bf ? bf2f(((const unsigned short*)src)[si]) : ((const float*)src)[si];
            dst[(j >> 6) * 4096 + k * 64 + (j & 63)] = v;
        } else if (i < 16384 + 320) {
            int t = i - 16384, which = t >> 6, k = t & 63;
            if (which == 4) prm[t] = 0.f;
            else {
                const void* p = (which == 0) ? bmv : (which == 1) ? buv
                              : (which == 2) ? gav : bev;
                prm[t] = bf ? bf2f(((const unsigned short*)p)[k]) : ((const float*)p)[k];
            }
        }
    }
    gridbar(cnt, gen);

    // ================= P1: bscan (block 0) + proj jobs ============================
    if (blk == 0) {
        int base = tid * 4;
        int c0 = (base + 0 < NBUCK) ? BktCnt[base + 0] : 0;
        int c1 = (base + 1 < NBUCK) ? BktCnt[base + 1] : 0;
        int c2 = (base + 2 < NBUCK) ? BktCnt[base + 2] : 0;
        int c3 = (base + 3 < NBUCK) ? BktCnt[base + 3] : 0;
        int s = c0 + c1 + c2 + c3;
        smem[tid] = s;
        __syncthreads();
        for (int off = 1; off < 256; off <<= 1) {
            int add = (tid >= off) ? smem[tid - off] : 0;
            __syncthreads();
            smem[tid] += add;
            __syncthreads();
        }
        int run = smem[tid] - s;
        if (base + 0 < NBUCK) { BktOff[base+0] = run; BktCur[base+0] = run; run += c0; }
        if (base + 1 < NBUCK) { BktOff[base+1] = run; BktCur[base+1] = run; run += c1; }
        if (base + 2 < NBUCK) { BktOff[base+2] = run; BktCur[base+2] = run; run += c2; }
        if (base + 3 < NBUCK) { BktOff[base+3] = run; BktCur[base+3] = run; run += c3; }
        if (tid == 255) BktOff[NBUCK] = smem[255];
    } else {
        m1_work(0, 2700, (blk - 1) * 4 + wib, (NBLK - 1) * 4,
                bf, lane, xv, WfMT, prm, Ps, Pt);
    }
    gridbar(cnt, gen);

    // ================= P2: bfill (blocks 0-127) + proj jobs =======================
    if (blk < 128) {
        int* h = smem; int* h2 = smem + NBUCK; int* basee = smem + 2 * NBUCK;
        for (int i = tid; i < NBUCK; i += 256) { h[i] = 0; h2[i] = 0; }
        __syncthreads();
        for (int e = blk * 256 + tid; e < NEDGES; e += 32768) {
            int tgt = i64 ? ei[4*e + 2] : ei[2*e + 1];
            if ((unsigned)tgt < NNODES) atomicAdd(&h[tgt / BKT], 1);
        }
        __syncthreads();
        for (int b = tid; b < NBUCK; b += 256)
            if (h[b]) basee[b] = atomicAdd(BktCur + b, h[b]);
        __syncthreads();
        for (int e = blk * 256 + tid; e < NEDGES; e += 32768) {
            int src, tgt;
            if (i64) { src = ei[4*e]; tgt = ei[4*e + 2]; }
            else     { src = ei[2*e]; tgt = ei[2*e + 1]; }
            if ((unsigned)tgt >= NNODES) continue;
            int b = tgt / BKT;
            int tl = tgt - b * BKT;
            int r = atomicAdd(&h2[b], 1);
            BktE[basee[b] + r] = (tl << 24) | (src & 0xFFFFFF);
        }
    } else {
        m1_work(2700, 2700, (blk - 128) * 4 + wib, (NBLK - 128) * 4,
                bf, lane, xv, WfMT, prm, Ps, Pt);
    }
    gridbar(cnt, gen);

    // ================= P3: tsort (blocks 0-249, 4 buckets each) + proj jobs =======
    if (blk < 250) {
        int* oc = smem; int* excl = smem + 128; int* cur = smem + 256;
        for (int bb = 0; bb < 4; ++bb) {
            int b = blk * 4 + bb;
            int s = BktOff[b], e = BktOff[b + 1];
            int n = e - s;
            if (tid < 128) oc[tid] = 0;
            __syncthreads();
            for (int i = tid; i < n; i += 256)
                atomicAdd(&oc[((unsigned)BktE[s + i]) >> 24], 1);
            __syncthreads();
            if (tid < 128) excl[tid] = (tid > 0) ? oc[tid - 1] : 0;
            __syncthreads();
            for (int off = 1; off < 128; off <<= 1) {
                int add = (tid >= off && tid < 128) ? excl[tid - off] : 0;
                __syncthreads();
                if (tid < 128) excl[tid] += add;
                __syncthreads();
            }
            if (tid < BKT) {
                Row[b * BKT + tid] = s + excl[tid];
                cur[tid] = excl[tid];
            }
            __syncthreads();
            for (int i = tid; i < n; i += 256) {
                int v = BktE[s + i];
                int tl = ((unsigned)v) >> 24;
                int p = atomicAdd(&cur[tl], 1);
                int sv = v & 0xFFFFFF;
                if (sv >= NNODES) sv = 0;
                CsrSrc[s + p] = sv << 6;   // pre-*DF
            }
            __syncthreads();
        }
        if (blk == 0 && tid == 0) Row[NNODES] = NEDGES;
    } else {
        m1_work(5400, 2600, (blk - 250) * 4 + wib, (NBLK - 250) * 4,
                bf, lane, xv, WfMT, prm, Ps, Pt);
    }
    gridbar(cnt, gen);

    // ================= P4: aggregation (all blocks; R10 body, inline searches) ====
    {
        int g = blk * 4 + wib;
        if (g < NCHUNK) {
            int eA = g * CHUNK;
            int lo = 0, hi = NNODES + 1;
            while (lo < hi) { int mid = (lo + hi) >> 1; if (Row[mid] >= eA) hi = mid; else lo = mid + 1; }
            int t_lo = lo;
            int t_hi;
            if (g == NCHUNK - 1) t_hi = NNODES;
            else {
                int hiB = eA + CHUNK;
                lo = t_lo; hi = NNODES + 1;
                while (lo < hi) { int mid = (lo + hi) >> 1; if (Row[mid] >= hiB) hi = mid; else lo = mid + 1; }
                t_hi = (lo > NNODES) ? NNODES : lo;
            }
            if (t_lo < t_hi) {
                int segS = Row[t_lo];
                for (int t = t_lo; t < t_hi; ++t) {
                    const int segE = Row[t + 1];
                    const int deg = segE - segS;
                    float ptv = bf2f(Pt[(size_t)t * DF + lane]);
                    float pa0 = 0.f, pa1 = 0.f, pa2 = 0.f, pa3 = 0.f;
                    for (int i = segS; i < segE; i += 16) {
                        #pragma unroll
                        for (int j = 0; j < 16; ++j) {
                            const int idx = i + j;
                            const int ok = idx < segE;
                            const int sv = CsrSrc[ok ? idx : segS];
                            float p = bf2f(Ps[(size_t)(unsigned)sv + lane]);
                            float v = ok ? fmaxf(p + ptv, 0.f) : 0.f;
                            if ((j & 3) == 0)      pa0 += v;
                            else if ((j & 3) == 1) pa1 += v;
                            else if ((j & 3) == 2) pa2 += v;
                            else                   pa3 += v;
                        }
                    }
                    float macc = (pa0 + pa1) + (pa2 + pa3);
                    float mval = (deg > 0) ? (macc / (float)deg) : 0.f;
                    Msg[(size_t)t * DF + lane] = f2bf(mval);
                    segS = segE;
                }
            }
        }
    }
    gridbar(cnt, gen);

    // ================= P5: t1 then u2, same wave/node-range (no extra sync) =======
    {
        int s5 = blk * 4 + wib;
        int n0 = s5 * NPW;
        if (n0 < NNODES) {
            int n1 = n0 + NPW;
            float* t1f = (float*)Ps;   // Ps/Pt dead after P4
            {   // pass A: t1 = x @ Wu_x^T + b_upd (fp32)
                float w[64];
                #pragma unroll
                for (int k = 0; k < 64; ++k) w[k] = WfUT[k * 64 + lane];
                const float bu_ = prm[64 + lane];
                for (int n = n0; n < n1; ++n)
                    t1f[(size_t)n * DF + lane] = dot64(xv, (size_t)n, bf, w) + bu_;
            }
            {   // pass B: u2 = LN(relu(t1 + Msg @ Wu_m^T) + x) — t1 read is own-thread
                float w[64];
                #pragma unroll
                for (int k = 0; k < 64; ++k) w[k] = WfUT[4096 + k * 64 + lane];
                const float ga_ = prm[128 + lane];
                const float be_ = prm[192 + lane];
                for (int n = n0; n < n1; ++n) {
                    float b0 = 0.f, b1 = 0.f, b2 = 0.f, b3 = 0.f;
                    const uint4* mw = (const uint4*)(Msg + (size_t)n * DF);
                    #pragma unroll
                    for (int q = 0; q < 8; ++q) {
                        uint4 v = mw[q];
                        float m0,m1,m2,m3,m4,m5,m6,m7;
                        unpack2(v.x, m0, m1); unpack2(v.y, m2, m3);
                        unpack2(v.z, m4, m5); unpack2(v.w, m6, m7);
                        b0 = fmaf(m0, w[8*q+0], b0); b1 = fmaf(m1, w[8*q+1], b1);
                        b2 = fmaf(m2, w[8*q+2], b2); b3 = fmaf(m3, w[8*q+3], b3);
                        b0 = fmaf(m4, w[8*q+4], b0); b1 = fmaf(m5, w[8*q+5], b1);
                        b2 = fmaf(m6, w[8*q+6], b2); b3 = fmaf(m7, w[8*q+7], b3);
                    }
                    size_t gi = (size_t)n * DF + lane;
                    float t  = t1f[gi];
                    float xl = bf ? bf2f(((const unsigned short*)xv)[gi])
                                  : ((const float*)xv)[gi];
                    float u = fmaxf((b0 + b1) + (b2 + b3) + t, 0.f);
                    float r = u + xl;

                    float s = r, s2 = r * r;
                    #pragma unroll
                    for (int m = 1; m < 64; m <<= 1) {
                        s  += __shfl_xor(s, m, 64);
                        s2 += __shfl_xor(s2, m, 64);
                    }
                    float mu  = s * (1.0f / 64.0f);
                    float var = fmaxf(s2 * (1.0f / 64.0f) - mu * mu, 0.f);
                    float o = (r - mu) * rsqrtf(var + 1e-5f) * ga_ + be_;

                    if (bf) ((__hip_bfloat16*)outv)[gi] = __float2bfloat16(o);
                    else    ((float*)outv)[gi] = o;
                }
            }
        }
    }
}

extern "C" void kernel_launch(void* const* d_in, const int* in_sizes, int n_in,
                              void* d_out, int out_size, void* d_ws, size_t ws_size,
                              hipStream_t stream) {
    const void* x  = d_in[0];
    const int*  ei = (const int*)d_in[1];
    const void* Wm = d_in[2];
    const void* bm = d_in[3];
    const void* Wu = d_in[4];
    const void* bu = d_in[5];
    const void* ga = d_in[6];
    const void* be = d_in[7];

    char* ws = (char*)d_ws;
    size_t off = 0;
    unsigned short* Ps  = (unsigned short*)(ws + off); off += (size_t)ND * 2;   // 12.8 MB
    unsigned short* Pt  = (unsigned short*)(ws + off); off += (size_t)ND * 2;   // 12.8 MB
    unsigned short* Msg = (unsigned short*)(ws + off); off += (size_t)ND * 2;   // 12.8 MB
    int*   BktE   = (int*)(ws + off); off += (size_t)NEDGES * 4;                // 6.4 MB
    int*   CsrSrc = (int*)(ws + off); off += (size_t)NEDGES * 4;                // 6.4 MB
    int*   Row    = (int*)(ws + off); off += (size_t)(NNODES + 1) * 4;
    int*   BktCnt = (int*)(ws + off); off += NBUCK * 4;                         // memset 0 (range start)
    int*   BktOff = (int*)(ws + off); off += (NBUCK + 1) * 4;
    int*   BktCur = (int*)(ws + off); off += NBUCK * 4;
    int*   flg    = (int*)(ws + off); off += 16;                                // barrier cnt/gen
    float* WfMT   = (float*)(ws + off); off += 8192 * 4;
    float* WfUT   = (float*)(ws + off); off += 8192 * 4;
    float* prm    = (float*)(ws + off); off += 320 * 4;

    // zero BktCnt..flg in one memset: 1000 + 1001 + 1000 ints + 16 B = 12020 B
    (void)hipMemsetAsync(BktCnt, 0, (size_t)(NBUCK + (NBUCK + 1) + NBUCK) * 4 + 16, stream);

    mega_k<<<NBLK, 256, 0, stream>>>(
        x, ei, Wm, bm, Wu, bu, ga, be,
        Ps, Pt, Msg, BktE, CsrSrc, Row,
        BktCnt, BktOff, BktCur, flg,
        WfMT, WfUT, prm, d_out);
}

// Round 17
// 332.879 us; speedup vs baseline: 9.8446x; 9.8446x over previous
//
#include <hip/hip_runtime.h>
#include <hip/hip_bf16.h>
#include <stdint.h>

#define NNODES 100000
#define DF 64
#define NEDGES 1600000
#define ND (NNODES * DF)     // 6,400,000
#define BKT 100              // targets per bucket
#define NBUCK 1000           // BKT*NBUCK == NNODES
#define CHUNK 128            // edges per wave in agg_k
#define NCHUNK (NEDGES / CHUNK)   // 12500
#define NPW 25               // nodes per wave in mm/u2 (4096 waves * 25 >= NNODES)

// ---------- helpers ----------
static __device__ __forceinline__ float bf2f(unsigned short u) {
    union { uint32_t i; float f; } c; c.i = ((uint32_t)u) << 16; return c.f;
}
static __device__ __forceinline__ unsigned short f2bf(float f) {
    union { __hip_bfloat16 b; unsigned short u; } c; c.b = __float2bfloat16(f); return c.u;
}
static __device__ __forceinline__ void unpack2(uint32_t u, float& lo, float& hi) {
    union { uint32_t i; float f; } a, b;
    a.i = u << 16; b.i = u & 0xFFFF0000u;
    lo = a.f; hi = b.f;
}

// ---------- dtype detector: flags[0]=bf16?, flags[1]=int64? ----------
__global__ void detect_k(const unsigned short* __restrict__ x,
                         const unsigned int* __restrict__ ei,
                         int* __restrict__ flags) {
    __shared__ int cnt_sane, cnt_odd_nz;
    if (threadIdx.x == 0) { cnt_sane = 0; cnt_odd_nz = 0; }
    __syncthreads();
    unsigned short s = x[threadIdx.x * 2];
    unsigned short m = s & 0x7FFF;
    if (m < 0x0080 || (m >= 0x3000 && m <= 0x4200)) atomicAdd(&cnt_sane, 1);
    if (threadIdx.x < 64) {
        if (ei[threadIdx.x * 2 + 1] != 0u) atomicAdd(&cnt_odd_nz, 1);
    }
    __syncthreads();
    if (threadIdx.x == 0) {
        flags[0] = (cnt_sane >= 192) ? 1 : 0;
        flags[1] = (cnt_odd_nz == 0) ? 1 : 0;
    }
}

// ---------- weight canonicalization -> fp32 TRANSPOSED ----------
// WfMT layout: [half][k][j] : half 0 = Wm_s, half 1 = Wm_t ; element = W[j][k]
// WfUT layout: half 0 = Wu_x, half 1 = Wu_m
// prm: [0:64)=b_msg [64:128)=b_upd [128:192)=gamma [192:256)=beta [256:320)=0
__global__ void wconv_k(const int* __restrict__ flags,
                        const void* __restrict__ Wm, const void* __restrict__ Wu,
                        const void* __restrict__ bm, const void* __restrict__ bu,
                        const void* __restrict__ ga, const void* __restrict__ be,
                        float* __restrict__ WfMT, float* __restrict__ WfUT,
                        float* __restrict__ prm) {
    const int bf = flags[0];
    int i = blockIdx.x * 256 + threadIdx.x;
    if (i < 16384) {
        const void* src = (i < 8192) ? Wm : Wu;
        float* dst = (i < 8192) ? WfMT : WfUT;
        int ii = i & 8191, j = ii >> 6, k = ii & 63;
        int si = (j & 63) * 128 + ((j >> 6) ? 64 : 0) + k;
        float v = bf ? bf2f(((const unsigned short*)src)[si]) : ((const float*)src)[si];
        dst[(j >> 6) * 4096 + k * 64 + (j & 63)] = v;
    } else if (i < 16384 + 320) {
        int t = i - 16384, which = t >> 6, k = t & 63;
        if (which == 4) { prm[t] = 0.f; }
        else {
            const void* p = (which == 0) ? bm : (which == 1) ? bu : (which == 2) ? ga : be;
            prm[t] = bf ? bf2f(((const unsigned short*)p)[k]) : ((const float*)p)[k];
        }
    }
}

// ---------- generic row-matmul: out[n][j] = sum_k in[n][k] * WT[k][j] + bias[j] ----------
// wave = contiguous run of NPW nodes (sequential row streaming), lane = output dim j.
// Weights in 64 registers per lane. of=1 -> fp32 out, of=0 -> bf16 out (row-major).
__global__ __launch_bounds__(256, 1) void mm_k(const int* __restrict__ flags,
                                               const void* __restrict__ xv,
                                               const float* __restrict__ WT,
                                               const float* __restrict__ bias,
                                               void* __restrict__ outv,
                                               int of) {
    const int lane = threadIdx.x & 63;
    const int wib = __builtin_amdgcn_readfirstlane(threadIdx.x >> 6);
    const int bf = flags[0];

    float w[64];
    #pragma unroll
    for (int k = 0; k < 64; ++k) w[k] = WT[k * 64 + lane];
    const float bs = bias[lane];

    const int wv = blockIdx.x * 4 + wib;
    const int n0 = wv * NPW;
    if (n0 >= NNODES) return;
    const int n1 = (n0 + NPW < NNODES) ? n0 + NPW : NNODES;
    for (int n = n0; n < n1; ++n) {
        float a0 = 0.f, a1 = 0.f, a2 = 0.f, a3 = 0.f;
        if (bf) {
            const uint4* xr = (const uint4*)((const unsigned short*)xv + (size_t)n * DF);
            #pragma unroll
            for (int q = 0; q < 8; ++q) {
                uint4 v = xr[q];
                float x0,x1,x2,x3,x4,x5,x6,x7;
                unpack2(v.x, x0, x1); unpack2(v.y, x2, x3);
                unpack2(v.z, x4, x5); unpack2(v.w, x6, x7);
                a0 = fmaf(x0, w[8*q+0], a0); a1 = fmaf(x1, w[8*q+1], a1);
                a2 = fmaf(x2, w[8*q+2], a2); a3 = fmaf(x3, w[8*q+3], a3);
                a0 = fmaf(x4, w[8*q+4], a0); a1 = fmaf(x5, w[8*q+5], a1);
                a2 = fmaf(x6, w[8*q+6], a2); a3 = fmaf(x7, w[8*q+7], a3);
            }
        } else {
            const float4* xr = (const float4*)((const float*)xv + (size_t)n * DF);
            #pragma unroll
            for (int q = 0; q < 16; ++q) {
                float4 v = xr[q];
                a0 = fmaf(v.x, w[4*q+0], a0); a1 = fmaf(v.y, w[4*q+1], a1);
                a2 = fmaf(v.z, w[4*q+2], a2); a3 = fmaf(v.w, w[4*q+3], a3);
            }
        }
        float r = (a0 + a1) + (a2 + a3) + bs;
        size_t gi = (size_t)n * DF + lane;
        if (of) ((float*)outv)[gi] = r;
        else    ((unsigned short*)outv)[gi] = f2bf(r);
    }
}

// ---------- bucket histogram (LDS pre-aggregated) ----------
__global__ __launch_bounds__(256) void bhist_k(const int* __restrict__ flags,
                                               const int* __restrict__ ei,
                                               int* __restrict__ BktCnt) {
    __shared__ int h[NBUCK];
    const int i64 = flags[1];
    for (int i = threadIdx.x; i < NBUCK; i += 256) h[i] = 0;
    __syncthreads();
    int stride = gridDim.x * 256;
    for (int e = blockIdx.x * 256 + threadIdx.x; e < NEDGES; e += stride) {
        int tgt = i64 ? ei[4*e + 2] : ei[2*e + 1];
        if ((unsigned)tgt < NNODES) atomicAdd(&h[tgt / BKT], 1);
    }
    __syncthreads();
    for (int b = threadIdx.x; b < NBUCK; b += 256)
        if (h[b]) atomicAdd(BktCnt + b, h[b]);
}

// ---------- scan of 1000 bucket counts ----------
__global__ __launch_bounds__(1024) void bscan_k(const int* __restrict__ BktCnt,
                                                int* __restrict__ BktOff,
                                                int* __restrict__ BktCur) {
    __shared__ int lds[1024];
    int t = threadIdx.x;
    int c = (t < NBUCK) ? BktCnt[t] : 0;
    lds[t] = c;
    __syncthreads();
    for (int off = 1; off < 1024; off <<= 1) {
        int add = (t >= off) ? lds[t - off] : 0;
        __syncthreads();
        lds[t] += add;
        __syncthreads();
    }
    if (t < NBUCK) {
        int ex = lds[t] - c;
        BktOff[t] = ex;
        BktCur[t] = ex;
    }
    if (t == NBUCK - 1) BktOff[NBUCK] = lds[t];
}

// ---------- bucket fill: two-pass binning, packed (tl<<24 | src) ----------
__global__ __launch_bounds__(256) void bfill_k(const int* __restrict__ flags,
                                               const int* __restrict__ ei,
                                               int* __restrict__ BktCur,
                                               int* __restrict__ BktE) {
    __shared__ int h[NBUCK], h2[NBUCK], basee[NBUCK];
    const int i64 = flags[1];
    for (int i = threadIdx.x; i < NBUCK; i += 256) { h[i] = 0; h2[i] = 0; }
    __syncthreads();
    const int stride = gridDim.x * 256;
    for (int e = blockIdx.x * 256 + threadIdx.x; e < NEDGES; e += stride) {
        int tgt = i64 ? ei[4*e + 2] : ei[2*e + 1];
        if ((unsigned)tgt < NNODES) atomicAdd(&h[tgt / BKT], 1);
    }
    __syncthreads();
    for (int b = threadIdx.x; b < NBUCK; b += 256)
        if (h[b]) basee[b] = atomicAdd(BktCur + b, h[b]);
    __syncthreads();
    for (int e = blockIdx.x * 256 + threadIdx.x; e < NEDGES; e += stride) {
        int src, tgt;
        if (i64) { src = ei[4*e]; tgt = ei[4*e + 2]; }
        else     { src = ei[2*e]; tgt = ei[2*e + 1]; }
        if ((unsigned)tgt >= NNODES) continue;
        int b = tgt / BKT;
        int tl = tgt - b * BKT;
        int r = atomicAdd(&h2[b], 1);
        BktE[basee[b] + r] = (tl << 24) | (src & 0xFFFFFF);
    }
}

// ---------- per-bucket counting sort by target -> CsrSrc + Row ----------
// CsrSrc entries are pre-clamped and PRE-MULTIPLIED by DF (row element offset),
// so agg_k's gather needs no clamp/shift.
__global__ __launch_bounds__(256) void tsort_k(const int* __restrict__ BktOff,
                                               const int* __restrict__ BktE,
                                               int* __restrict__ CsrSrc,
                                               int* __restrict__ Row) {
    __shared__ int oc[128], excl[128], cur[128];
    const int tid = threadIdx.x;
    const int b = blockIdx.x;
    const int s = BktOff[b], e = BktOff[b + 1];
    const int n = e - s;
    if (tid < 128) { oc[tid] = 0; }
    __syncthreads();
    for (int i = tid; i < n; i += 256)
        atomicAdd(&oc[((unsigned)BktE[s + i]) >> 24], 1);
    __syncthreads();
    if (tid < 128) excl[tid] = (tid > 0) ? oc[tid - 1] : 0;
    __syncthreads();
    for (int off = 1; off < 128; off <<= 1) {
        int add = (tid >= off && tid < 128) ? excl[tid - off] : 0;
        __syncthreads();
        if (tid < 128) excl[tid] += add;
        __syncthreads();
    }
    if (tid < BKT) {
        Row[b * BKT + tid] = s + excl[tid];
        cur[tid] = excl[tid];
    }
    if (b == 0 && tid == 0) Row[NNODES] = NEDGES;
    __syncthreads();
    for (int i = tid; i < n; i += 256) {
        int v = BktE[s + i];
        int tl = ((unsigned)v) >> 24;
        int p = atomicAdd(&cur[tl], 1);
        int sv = v & 0xFFFFFF;
        if (sv >= NNODES) sv = 0;
        CsrSrc[s + p] = sv << 6;   // * DF
    }
}

// ---------- chunk -> first-target table (hoists agg's binary searches) ----------
__global__ __launch_bounds__(256) void cstart_k(const int* __restrict__ Row,
                                                int* __restrict__ ChunkT) {
    int c = blockIdx.x * 256 + threadIdx.x;
    if (c > NCHUNK) return;
    if (c == NCHUNK) { ChunkT[NCHUNK] = NNODES; return; }
    int target = c * CHUNK;
    int lo = 0, hi = NNODES + 1;
    while (lo < hi) { int mid = (lo + hi) >> 1; if (Row[mid] >= target) hi = mid; else lo = mid + 1; }
    ChunkT[c] = lo;
}

// ---------- aggregation: lane = dim, masked-16 gather pipeline (R10 optimum) ----------
__global__ __launch_bounds__(256) void agg_k(const unsigned short* __restrict__ Ps,
                                             const unsigned short* __restrict__ Pt,
                                             const int* __restrict__ Row,
                                             const int* __restrict__ CsrSrc,
                                             const int* __restrict__ ChunkT,
                                             unsigned short* __restrict__ Msg) {
    const int lane = threadIdx.x & 63;
    const int wib = __builtin_amdgcn_readfirstlane(threadIdx.x >> 6);
    const int w = blockIdx.x * 4 + wib;
    if (w >= NCHUNK) return;

    const int t_lo = ChunkT[w];
    const int t_hi = ChunkT[w + 1];
    if (t_lo >= t_hi) return;

    int segS = Row[t_lo];
    for (int t = t_lo; t < t_hi; ++t) {
        const int segE = Row[t + 1];
        const int deg = segE - segS;
        float ptv = bf2f(Pt[(size_t)t * DF + lane]);
        float pa0 = 0.f, pa1 = 0.f, pa2 = 0.f, pa3 = 0.f;
        for (int i = segS; i < segE; i += 16) {
            #pragma unroll
            for (int j = 0; j < 16; ++j) {
                const int idx = i + j;
                const int ok = idx < segE;
                const int sv = CsrSrc[ok ? idx : segS];   // pre-clamped, pre-*DF
                float p = bf2f(Ps[(size_t)(unsigned)sv + lane]);
                float v = ok ? fmaxf(p + ptv, 0.f) : 0.f;
                if ((j & 3) == 0)      pa0 += v;
                else if ((j & 3) == 1) pa1 += v;
                else if ((j & 3) == 2) pa2 += v;
                else                   pa3 += v;
            }
        }
        float macc = (pa0 + pa1) + (pa2 + pa3);
        float mval = (deg > 0) ? (macc / (float)deg) : 0.f;
        Msg[(size_t)t * DF + lane] = f2bf(mval);
        segS = segE;
    }
}

// ---------- u2: r = relu(t1 + Msg@Wu_m^T) + x ; LayerNorm ; out ----------
// wave = contiguous run of NPW nodes, lane = dim. Wu_m (64 floats) in registers.
__global__ __launch_bounds__(256, 1) void u2_k(const int* __restrict__ flags,
                                               const void* __restrict__ xv,
                                               const unsigned short* __restrict__ Msg,
                                               const float* __restrict__ t1,
                                               const float* __restrict__ WT,
                                               const float* __restrict__ prm,
                                               void* __restrict__ outv) {
    const int lane = threadIdx.x & 63;
    const int wib = __builtin_amdgcn_readfirstlane(threadIdx.x >> 6);
    const int bf = flags[0];

    float w[64];
    #pragma unroll
    for (int k = 0; k < 64; ++k) w[k] = WT[k * 64 + lane];
    const float ga = prm[128 + lane];
    const float be = prm[192 + lane];

    const unsigned short* x16 = (const unsigned short*)xv;
    const float* xf = (const float*)xv;

    const int wv = blockIdx.x * 4 + wib;
    const int n0 = wv * NPW;
    if (n0 >= NNODES) return;
    const int n1 = (n0 + NPW < NNODES) ? n0 + NPW : NNODES;
    for (int n = n0; n < n1; ++n) {
        float b0 = 0.f, b1 = 0.f, b2 = 0.f, b3 = 0.f;
        const uint4* mw = (const uint4*)(Msg + (size_t)n * DF);
        #pragma unroll
        for (int q = 0; q < 8; ++q) {
            uint4 v = mw[q];
            float m0,m1,m2,m3,m4,m5,m6,m7;
            unpack2(v.x, m0, m1); unpack2(v.y, m2, m3);
            unpack2(v.z, m4, m5); unpack2(v.w, m6, m7);
            b0 = fmaf(m0, w[8*q+0], b0); b1 = fmaf(m1, w[8*q+1], b1);
            b2 = fmaf(m2, w[8*q+2], b2); b3 = fmaf(m3, w[8*q+3], b3);
            b0 = fmaf(m4, w[8*q+4], b0); b1 = fmaf(m5, w[8*q+5], b1);
            b2 = fmaf(m6, w[8*q+6], b2); b3 = fmaf(m7, w[8*q+7], b3);
        }
        size_t gi = (size_t)n * DF + lane;
        float t  = t1[gi];
        float xl = bf ? bf2f(x16[gi]) : xf[gi];
        float u = fmaxf((b0 + b1) + (b2 + b3) + t, 0.f);
        float r = u + xl;

        float s = r, s2 = r * r;
        #pragma unroll
        for (int m = 1; m < 64; m <<= 1) {
            s  += __shfl_xor(s, m, 64);
            s2 += __shfl_xor(s2, m, 64);
        }
        float mu  = s * (1.0f / 64.0f);
        float var = fmaxf(s2 * (1.0f / 64.0f) - mu * mu, 0.f);
        float o = (r - mu) * rsqrtf(var + 1e-5f) * ga + be;

        if (bf) ((__hip_bfloat16*)outv)[gi] = __float2bfloat16(o);
        else    ((float*)outv)[gi] = o;
    }
}

extern "C" void kernel_launch(void* const* d_in, const int* in_sizes, int n_in,
                              void* d_out, int out_size, void* d_ws, size_t ws_size,
                              hipStream_t stream) {
    const void* x  = d_in[0];
    const int*  ei = (const int*)d_in[1];
    const void* Wm = d_in[2];
    const void* bm = d_in[3];
    const void* Wu = d_in[4];
    const void* bu = d_in[5];
    const void* ga = d_in[6];
    const void* be = d_in[7];

    char* ws = (char*)d_ws;
    size_t off = 0;
    unsigned short* Ps  = (unsigned short*)(ws + off); off += (size_t)ND * 2;   // 12.8 MB
    unsigned short* Pt  = (unsigned short*)(ws + off); off += (size_t)ND * 2;   // 12.8 MB
    unsigned short* Msg = (unsigned short*)(ws + off); off += (size_t)ND * 2;   // 12.8 MB
    int*   BktE   = (int*)(ws + off); off += (size_t)NEDGES * 4;                // 6.4 MB
    int*   CsrSrc = (int*)(ws + off); off += (size_t)NEDGES * 4;                // 6.4 MB
    int*   Row    = (int*)(ws + off); off += (size_t)(NNODES + 1) * 4;
    int*   BktCnt = (int*)(ws + off); off += NBUCK * 4;                         // memset 0
    int*   BktOff = (int*)(ws + off); off += (NBUCK + 1) * 4;
    int*   BktCur = (int*)(ws + off); off += NBUCK * 4;
    int*   flg    = (int*)(ws + off); off += 16;
    float* WfMT   = (float*)(ws + off); off += 8192 * 4;
    float* WfUT   = (float*)(ws + off); off += 8192 * 4;
    float* prm    = (float*)(ws + off); off += 320 * 4;

    // t1 (fp32, 25.6 MB) reuses Ps+Pt region — valid because mm_k(t1) runs AFTER agg_k.
    float* t1 = (float*)Ps;
    // ChunkT (12501 ints) aliases BktE — dead after tsort_k.
    int* ChunkT = BktE;

    (void)hipMemsetAsync(BktCnt, 0, NBUCK * 4, stream);

    detect_k<<<1, 256, 0, stream>>>((const unsigned short*)x, (const unsigned int*)ei, flg);
    // 66 blocks: covers 16384 weight elems + 320 prm elems
    wconv_k<<<66, 256, 0, stream>>>(flg, Wm, Wu, bm, bu, ga, be, WfMT, WfUT, prm);

    // Ps = x@Wm_s^T (no bias -> zero slot prm+256) ; Pt = x@Wm_t^T + b_msg
    mm_k<<<1024, 256, 0, stream>>>(flg, x, WfMT,        prm + 256, Ps, 0);
    mm_k<<<1024, 256, 0, stream>>>(flg, x, WfMT + 4096, prm,       Pt, 0);

    bhist_k<<<256, 256, 0, stream>>>(flg, ei, BktCnt);
    bscan_k<<<1, 1024, 0, stream>>>(BktCnt, BktOff, BktCur);
    bfill_k<<<128, 256, 0, stream>>>(flg, ei, BktCur, BktE);
    tsort_k<<<NBUCK, 256, 0, stream>>>(BktOff, BktE, CsrSrc, Row);

    // chunk->target table (one search per chunk; BktE is dead, reuse as ChunkT)
    cstart_k<<<(NCHUNK + 256) / 256, 256, 0, stream>>>(Row, ChunkT);

    agg_k<<<(NCHUNK + 3) / 4, 256, 0, stream>>>(Ps, Pt, Row, CsrSrc, ChunkT, Msg);

    // t1 = x@Wu_x^T + b_upd (fp32 row-major), overwrites Ps/Pt (now dead)
    mm_k<<<1024, 256, 0, stream>>>(flg, x, WfUT, prm + 64, t1, 1);

    u2_k<<<1024, 256, 0, stream>>>(flg, x, Msg, t1, WfUT + 4096, prm, d_out);
}

// Round 18
// 321.698 us; speedup vs baseline: 10.1867x; 1.0348x over previous
//
#include <hip/hip_runtime.h>
#include <hip/hip_bf16.h>
#include <stdint.h>

#define NNODES 100000
#define DF 64
#define NEDGES 1600000
#define ND (NNODES * DF)     // 6,400,000
#define BKT 100              // targets per bucket
#define NBUCK 1000           // BKT*NBUCK == NNODES
#define CHUNK 128            // edges per wave in agg_k
#define NCHUNK (NEDGES / CHUNK)   // 12500
#define NPW 25               // nodes per wave in mm/u2 (4096 waves * 25 >= NNODES)

// ---------- helpers ----------
static __device__ __forceinline__ float bf2f(unsigned short u) {
    union { uint32_t i; float f; } c; c.i = ((uint32_t)u) << 16; return c.f;
}
static __device__ __forceinline__ unsigned short f2bf(float f) {
    union { __hip_bfloat16 b; unsigned short u; } c; c.b = __float2bfloat16(f); return c.u;
}
static __device__ __forceinline__ void unpack2(uint32_t u, float& lo, float& hi) {
    union { uint32_t i; float f; } a, b;
    a.i = u << 16; b.i = u & 0xFFFF0000u;
    lo = a.f; hi = b.f;
}

// ---------- weight canonicalization + inline dtype detection (R13-verified) ----------
// Every block derives flags locally (reads 256 shorts + 64 ints); block 0
// publishes to flg for downstream kernels.
// WfMT layout: [half][k][j], half 0 = Wm_s, half 1 = Wm_t ; element = W[j][k]
// WfUT layout: half 0 = Wu_x, half 1 = Wu_m
// prm: [0:64)=b_msg [64:128)=b_upd [128:192)=gamma [192:256)=beta [256:320)=0
__global__ void wconv_k(const unsigned short* __restrict__ x,
                        const unsigned int* __restrict__ eiu,
                        const void* __restrict__ Wm, const void* __restrict__ Wu,
                        const void* __restrict__ bm, const void* __restrict__ bu,
                        const void* __restrict__ ga, const void* __restrict__ be,
                        float* __restrict__ WfMT, float* __restrict__ WfUT,
                        float* __restrict__ prm, int* __restrict__ flags) {
    __shared__ int cnt_sane, cnt_odd_nz;
    if (threadIdx.x == 0) { cnt_sane = 0; cnt_odd_nz = 0; }
    __syncthreads();
    {
        unsigned short s = x[threadIdx.x * 2];
        unsigned short m = s & 0x7FFF;
        if (m < 0x0080 || (m >= 0x3000 && m <= 0x4200)) atomicAdd(&cnt_sane, 1);
        if (threadIdx.x < 64) {
            if (eiu[threadIdx.x * 2 + 1] != 0u) atomicAdd(&cnt_odd_nz, 1);
        }
    }
    __syncthreads();
    const int bf = (cnt_sane >= 192) ? 1 : 0;
    if (blockIdx.x == 0 && threadIdx.x == 0) {
        flags[0] = bf;
        flags[1] = (cnt_odd_nz == 0) ? 1 : 0;
    }
    int i = blockIdx.x * 256 + threadIdx.x;
    if (i < 16384) {
        const void* src = (i < 8192) ? Wm : Wu;
        float* dst = (i < 8192) ? WfMT : WfUT;
        int ii = i & 8191, j = ii >> 6, k = ii & 63;
        int si = (j & 63) * 128 + ((j >> 6) ? 64 : 0) + k;
        float v = bf ? bf2f(((const unsigned short*)src)[si]) : ((const float*)src)[si];
        dst[(j >> 6) * 4096 + k * 64 + (j & 63)] = v;
    } else if (i < 16384 + 320) {
        int t = i - 16384, which = t >> 6, k = t & 63;
        if (which == 4) { prm[t] = 0.f; }
        else {
            const void* p = (which == 0) ? bm : (which == 1) ? bu : (which == 2) ? ga : be;
            prm[t] = bf ? bf2f(((const unsigned short*)p)[k]) : ((const float*)p)[k];
        }
    }
}

// ---------- fused phase-1: proj(Ps) + proj(Pt) + bhist, disjoint block ranges ----------
// Blocks [0,1024): Ps = x@Wm_s^T. Blocks [1024,2048): Pt = x@Wm_t^T + b_msg.
// Blocks [2048,2304): LDS-bucket histogram. Branches are INDEPENDENT (no sync,
// no shared dataflow) and each is byte-structurally the proven standalone kernel.
// launch_bounds(256,1): allocator free to keep w[64] resident (R16 lesson: a
// min-occupancy bound caps VGPRs and forces the weight array to scratch).
__global__ __launch_bounds__(256, 1) void pj_k(const int* __restrict__ flags,
                                               const void* __restrict__ xv,
                                               const float* __restrict__ WfMT,
                                               const float* __restrict__ prm,
                                               unsigned short* __restrict__ Ps,
                                               unsigned short* __restrict__ Pt,
                                               const int* __restrict__ ei,
                                               int* __restrict__ BktCnt) {
    const int blk = blockIdx.x;
    if (blk < 2048) {
        const int lane = threadIdx.x & 63;
        const int wib = __builtin_amdgcn_readfirstlane(threadIdx.x >> 6);
        const int bf = flags[0];
        const int mtx = (blk >= 1024);           // block-uniform
        const float* WT = WfMT + (mtx ? 4096 : 0);

        float w[64];
        #pragma unroll
        for (int k = 0; k < 64; ++k) w[k] = WT[k * 64 + lane];
        const float bs = mtx ? prm[lane] : 0.f;
        unsigned short* outp = mtx ? Pt : Ps;

        const int wv = (blk & 1023) * 4 + wib;
        const int n0 = wv * NPW;
        if (n0 >= NNODES) return;
        const int n1 = (n0 + NPW < NNODES) ? n0 + NPW : NNODES;
        for (int n = n0; n < n1; ++n) {
            float a0 = 0.f, a1 = 0.f, a2 = 0.f, a3 = 0.f;
            if (bf) {
                const uint4* xr = (const uint4*)((const unsigned short*)xv + (size_t)n * DF);
                #pragma unroll
                for (int q = 0; q < 8; ++q) {
                    uint4 v = xr[q];
                    float x0,x1,x2,x3,x4,x5,x6,x7;
                    unpack2(v.x, x0, x1); unpack2(v.y, x2, x3);
                    unpack2(v.z, x4, x5); unpack2(v.w, x6, x7);
                    a0 = fmaf(x0, w[8*q+0], a0); a1 = fmaf(x1, w[8*q+1], a1);
                    a2 = fmaf(x2, w[8*q+2], a2); a3 = fmaf(x3, w[8*q+3], a3);
                    a0 = fmaf(x4, w[8*q+4], a0); a1 = fmaf(x5, w[8*q+5], a1);
                    a2 = fmaf(x6, w[8*q+6], a2); a3 = fmaf(x7, w[8*q+7], a3);
                }
            } else {
                const float4* xr = (const float4*)((const float*)xv + (size_t)n * DF);
                #pragma unroll
                for (int q = 0; q < 16; ++q) {
                    float4 v = xr[q];
                    a0 = fmaf(v.x, w[4*q+0], a0); a1 = fmaf(v.y, w[4*q+1], a1);
                    a2 = fmaf(v.z, w[4*q+2], a2); a3 = fmaf(v.w, w[4*q+3], a3);
                }
            }
            outp[(size_t)n * DF + lane] = f2bf((a0 + a1) + (a2 + a3) + bs);
        }
    } else {
        // ---- bhist branch: 256 blocks, LDS pre-aggregated ----
        __shared__ int h[NBUCK];
        const int i64 = flags[1];
        const int hb = blk - 2048;
        for (int i = threadIdx.x; i < NBUCK; i += 256) h[i] = 0;
        __syncthreads();
        for (int e = hb * 256 + threadIdx.x; e < NEDGES; e += 65536) {
            int tgt = i64 ? ei[4*e + 2] : ei[2*e + 1];
            if ((unsigned)tgt < NNODES) atomicAdd(&h[tgt / BKT], 1);
        }
        __syncthreads();
        for (int b = threadIdx.x; b < NBUCK; b += 256)
            if (h[b]) atomicAdd(BktCnt + b, h[b]);
    }
}

// ---------- scan of 1000 bucket counts (R10/R17) ----------
__global__ __launch_bounds__(1024) void bscan_k(const int* __restrict__ BktCnt,
                                                int* __restrict__ BktOff,
                                                int* __restrict__ BktCur) {
    __shared__ int lds[1024];
    int t = threadIdx.x;
    int c = (t < NBUCK) ? BktCnt[t] : 0;
    lds[t] = c;
    __syncthreads();
    for (int off = 1; off < 1024; off <<= 1) {
        int add = (t >= off) ? lds[t - off] : 0;
        __syncthreads();
        lds[t] += add;
        __syncthreads();
    }
    if (t < NBUCK) {
        int ex = lds[t] - c;
        BktOff[t] = ex;
        BktCur[t] = ex;
    }
    if (t == NBUCK - 1) BktOff[NBUCK] = lds[t];
}

// ---------- bucket fill: two-pass binning, packed (tl<<24 | src) (R10/R17) ----------
__global__ __launch_bounds__(256) void bfill_k(const int* __restrict__ flags,
                                               const int* __restrict__ ei,
                                               int* __restrict__ BktCur,
                                               int* __restrict__ BktE) {
    __shared__ int h[NBUCK], h2[NBUCK], basee[NBUCK];
    const int i64 = flags[1];
    for (int i = threadIdx.x; i < NBUCK; i += 256) { h[i] = 0; h2[i] = 0; }
    __syncthreads();
    const int stride = gridDim.x * 256;
    for (int e = blockIdx.x * 256 + threadIdx.x; e < NEDGES; e += stride) {
        int tgt = i64 ? ei[4*e + 2] : ei[2*e + 1];
        if ((unsigned)tgt < NNODES) atomicAdd(&h[tgt / BKT], 1);
    }
    __syncthreads();
    for (int b = threadIdx.x; b < NBUCK; b += 256)
        if (h[b]) basee[b] = atomicAdd(BktCur + b, h[b]);
    __syncthreads();
    for (int e = blockIdx.x * 256 + threadIdx.x; e < NEDGES; e += stride) {
        int src, tgt;
        if (i64) { src = ei[4*e]; tgt = ei[4*e + 2]; }
        else     { src = ei[2*e]; tgt = ei[2*e + 1]; }
        if ((unsigned)tgt >= NNODES) continue;
        int b = tgt / BKT;
        int tl = tgt - b * BKT;
        int r = atomicAdd(&h2[b], 1);
        BktE[basee[b] + r] = (tl << 24) | (src & 0xFFFFFF);
    }
}

// ---------- per-bucket counting sort by target -> CsrSrc + Row (R10/R17) ----------
// CsrSrc entries are pre-clamped and PRE-MULTIPLIED by DF.
__global__ __launch_bounds__(256) void tsort_k(const int* __restrict__ BktOff,
                                               const int* __restrict__ BktE,
                                               int* __restrict__ CsrSrc,
                                               int* __restrict__ Row) {
    __shared__ int oc[128], excl[128], cur[128];
    const int tid = threadIdx.x;
    const int b = blockIdx.x;
    const int s = BktOff[b], e = BktOff[b + 1];
    const int n = e - s;
    if (tid < 128) { oc[tid] = 0; }
    __syncthreads();
    for (int i = tid; i < n; i += 256)
        atomicAdd(&oc[((unsigned)BktE[s + i]) >> 24], 1);
    __syncthreads();
    if (tid < 128) excl[tid] = (tid > 0) ? oc[tid - 1] : 0;
    __syncthreads();
    for (int off = 1; off < 128; off <<= 1) {
        int add = (tid >= off && tid < 128) ? excl[tid - off] : 0;
        __syncthreads();
        if (tid < 128) excl[tid] += add;
        __syncthreads();
    }
    if (tid < BKT) {
        Row[b * BKT + tid] = s + excl[tid];
        cur[tid] = excl[tid];
    }
    if (b == 0 && tid == 0) Row[NNODES] = NEDGES;
    __syncthreads();
    for (int i = tid; i < n; i += 256) {
        int v = BktE[s + i];
        int tl = ((unsigned)v) >> 24;
        int p = atomicAdd(&cur[tl], 1);
        int sv = v & 0xFFFFFF;
        if (sv >= NNODES) sv = 0;
        CsrSrc[s + p] = sv << 6;   // * DF
    }
}

// ---------- chunk -> first-target table (R10/R17) ----------
__global__ __launch_bounds__(256) void cstart_k(const int* __restrict__ Row,
                                                int* __restrict__ ChunkT) {
    int c = blockIdx.x * 256 + threadIdx.x;
    if (c > NCHUNK) return;
    if (c == NCHUNK) { ChunkT[NCHUNK] = NNODES; return; }
    int target = c * CHUNK;
    int lo = 0, hi = NNODES + 1;
    while (lo < hi) { int mid = (lo + hi) >> 1; if (Row[mid] >= target) hi = mid; else lo = mid + 1; }
    ChunkT[c] = lo;
}

// ---------- aggregation: lane = dim, masked-16 gather pipeline (R10 optimum) ----------
__global__ __launch_bounds__(256) void agg_k(const unsigned short* __restrict__ Ps,
                                             const unsigned short* __restrict__ Pt,
                                             const int* __restrict__ Row,
                                             const int* __restrict__ CsrSrc,
                                             const int* __restrict__ ChunkT,
                                             unsigned short* __restrict__ Msg) {
    const int lane = threadIdx.x & 63;
    const int wib = __builtin_amdgcn_readfirstlane(threadIdx.x >> 6);
    const int w = blockIdx.x * 4 + wib;
    if (w >= NCHUNK) return;

    const int t_lo = ChunkT[w];
    const int t_hi = ChunkT[w + 1];
    if (t_lo >= t_hi) return;

    int segS = Row[t_lo];
    for (int t = t_lo; t < t_hi; ++t) {
        const int segE = Row[t + 1];
        const int deg = segE - segS;
        float ptv = bf2f(Pt[(size_t)t * DF + lane]);
        float pa0 = 0.f, pa1 = 0.f, pa2 = 0.f, pa3 = 0.f;
        for (int i = segS; i < segE; i += 16) {
            #pragma unroll
            for (int j = 0; j < 16; ++j) {
                const int idx = i + j;
                const int ok = idx < segE;
                const int sv = CsrSrc[ok ? idx : segS];   // pre-clamped, pre-*DF
                float p = bf2f(Ps[(size_t)(unsigned)sv + lane]);
                float v = ok ? fmaxf(p + ptv, 0.f) : 0.f;
                if ((j & 3) == 0)      pa0 += v;
                else if ((j & 3) == 1) pa1 += v;
                else if ((j & 3) == 2) pa2 += v;
                else                   pa3 += v;
            }
        }
        float macc = (pa0 + pa1) + (pa2 + pa3);
        float mval = (deg > 0) ? (macc / (float)deg) : 0.f;
        Msg[(size_t)t * DF + lane] = f2bf(mval);
        segS = segE;
    }
}

// ---------- generic row-matmul (R17, used for t1 only now) ----------
__global__ __launch_bounds__(256, 1) void mm_k(const int* __restrict__ flags,
                                               const void* __restrict__ xv,
                                               const float* __restrict__ WT,
                                               const float* __restrict__ bias,
                                               void* __restrict__ outv,
                                               int of) {
    const int lane = threadIdx.x & 63;
    const int wib = __builtin_amdgcn_readfirstlane(threadIdx.x >> 6);
    const int bf = flags[0];

    float w[64];
    #pragma unroll
    for (int k = 0; k < 64; ++k) w[k] = WT[k * 64 + lane];
    const float bs = bias[lane];

    const int wv = blockIdx.x * 4 + wib;
    const int n0 = wv * NPW;
    if (n0 >= NNODES) return;
    const int n1 = (n0 + NPW < NNODES) ? n0 + NPW : NNODES;
    for (int n = n0; n < n1; ++n) {
        float a0 = 0.f, a1 = 0.f, a2 = 0.f, a3 = 0.f;
        if (bf) {
            const uint4* xr = (const uint4*)((const unsigned short*)xv + (size_t)n * DF);
            #pragma unroll
            for (int q = 0; q < 8; ++q) {
                uint4 v = xr[q];
                float x0,x1,x2,x3,x4,x5,x6,x7;
                unpack2(v.x, x0, x1); unpack2(v.y, x2, x3);
                unpack2(v.z, x4, x5); unpack2(v.w, x6, x7);
                a0 = fmaf(x0, w[8*q+0], a0); a1 = fmaf(x1, w[8*q+1], a1);
                a2 = fmaf(x2, w[8*q+2], a2); a3 = fmaf(x3, w[8*q+3], a3);
                a0 = fmaf(x4, w[8*q+4], a0); a1 = fmaf(x5, w[8*q+5], a1);
                a2 = fmaf(x6, w[8*q+6], a2); a3 = fmaf(x7, w[8*q+7], a3);
            }
        } else {
            const float4* xr = (const float4*)((const float*)xv + (size_t)n * DF);
            #pragma unroll
            for (int q = 0; q < 16; ++q) {
                float4 v = xr[q];
                a0 = fmaf(v.x, w[4*q+0], a0); a1 = fmaf(v.y, w[4*q+1], a1);
                a2 = fmaf(v.z, w[4*q+2], a2); a3 = fmaf(v.w, w[4*q+3], a3);
            }
        }
        float r = (a0 + a1) + (a2 + a3) + bs;
        size_t gi = (size_t)n * DF + lane;
        if (of) ((float*)outv)[gi] = r;
        else    ((unsigned short*)outv)[gi] = f2bf(r);
    }
}

// ---------- u2: r = relu(t1 + Msg@Wu_m^T) + x ; LayerNorm ; out (R10/R17) ----------
__global__ __launch_bounds__(256, 1) void u2_k(const int* __restrict__ flags,
                                               const void* __restrict__ xv,
                                               const unsigned short* __restrict__ Msg,
                                               const float* __restrict__ t1,
                                               const float* __restrict__ WT,
                                               const float* __restrict__ prm,
                                               void* __restrict__ outv) {
    const int lane = threadIdx.x & 63;
    const int wib = __builtin_amdgcn_readfirstlane(threadIdx.x >> 6);
    const int bf = flags[0];

    float w[64];
    #pragma unroll
    for (int k = 0; k < 64; ++k) w[k] = WT[k * 64 + lane];
    const float ga = prm[128 + lane];
    const float be = prm[192 + lane];

    const unsigned short* x16 = (const unsigned short*)xv;
    const float* xf = (const float*)xv;

    const int wv = blockIdx.x * 4 + wib;
    const int n0 = wv * NPW;
    if (n0 >= NNODES) return;
    const int n1 = (n0 + NPW < NNODES) ? n0 + NPW : NNODES;
    for (int n = n0; n < n1; ++n) {
        float b0 = 0.f, b1 = 0.f, b2 = 0.f, b3 = 0.f;
        const uint4* mw = (const uint4*)(Msg + (size_t)n * DF);
        #pragma unroll
        for (int q = 0; q < 8; ++q) {
            uint4 v = mw[q];
            float m0,m1,m2,m3,m4,m5,m6,m7;
            unpack2(v.x, m0, m1); unpack2(v.y, m2, m3);
            unpack2(v.z, m4, m5); unpack2(v.w, m6, m7);
            b0 = fmaf(m0, w[8*q+0], b0); b1 = fmaf(m1, w[8*q+1], b1);
            b2 = fmaf(m2, w[8*q+2], b2); b3 = fmaf(m3, w[8*q+3], b3);
            b0 = fmaf(m4, w[8*q+4], b0); b1 = fmaf(m5, w[8*q+5], b1);
            b2 = fmaf(m6, w[8*q+6], b2); b3 = fmaf(m7, w[8*q+7], b3);
        }
        size_t gi = (size_t)n * DF + lane;
        float t  = t1[gi];
        float xl = bf ? bf2f(x16[gi]) : xf[gi];
        float u = fmaxf((b0 + b1) + (b2 + b3) + t, 0.f);
        float r = u + xl;

        float s = r, s2 = r * r;
        #pragma unroll
        for (int m = 1; m < 64; m <<= 1) {
            s  += __shfl_xor(s, m, 64);
            s2 += __shfl_xor(s2, m, 64);
        }
        float mu  = s * (1.0f / 64.0f);
        float var = fmaxf(s2 * (1.0f / 64.0f) - mu * mu, 0.f);
        float o = (r - mu) * rsqrtf(var + 1e-5f) * ga + be;

        if (bf) ((__hip_bfloat16*)outv)[gi] = __float2bfloat16(o);
        else    ((float*)outv)[gi] = o;
    }
}

extern "C" void kernel_launch(void* const* d_in, const int* in_sizes, int n_in,
                              void* d_out, int out_size, void* d_ws, size_t ws_size,
                              hipStream_t stream) {
    const void* x  = d_in[0];
    const int*  ei = (const int*)d_in[1];
    const void* Wm = d_in[2];
    const void* bm = d_in[3];
    const void* Wu = d_in[4];
    const void* bu = d_in[5];
    const void* ga = d_in[6];
    const void* be = d_in[7];

    char* ws = (char*)d_ws;
    size_t off = 0;
    unsigned short* Ps  = (unsigned short*)(ws + off); off += (size_t)ND * 2;   // 12.8 MB
    unsigned short* Pt  = (unsigned short*)(ws + off); off += (size_t)ND * 2;   // 12.8 MB
    unsigned short* Msg = (unsigned short*)(ws + off); off += (size_t)ND * 2;   // 12.8 MB
    int*   BktE   = (int*)(ws + off); off += (size_t)NEDGES * 4;                // 6.4 MB
    int*   CsrSrc = (int*)(ws + off); off += (size_t)NEDGES * 4;                // 6.4 MB
    int*   Row    = (int*)(ws + off); off += (size_t)(NNODES + 1) * 4;
    int*   BktCnt = (int*)(ws + off); off += NBUCK * 4;                         // memset 0
    int*   BktOff = (int*)(ws + off); off += (NBUCK + 1) * 4;
    int*   BktCur = (int*)(ws + off); off += NBUCK * 4;
    int*   flg    = (int*)(ws + off); off += 16;
    float* WfMT   = (float*)(ws + off); off += 8192 * 4;
    float* WfUT   = (float*)(ws + off); off += 8192 * 4;
    float* prm    = (float*)(ws + off); off += 320 * 4;

    // t1 (fp32, 25.6 MB) reuses Ps+Pt region — valid because mm_k(t1) runs AFTER agg_k.
    float* t1 = (float*)Ps;
    // ChunkT (12501 ints) aliases BktE — dead after tsort_k.
    int* ChunkT = BktE;

    (void)hipMemsetAsync(BktCnt, 0, NBUCK * 4, stream);

    // wconv with inline dtype detection (saves detect_k launch)
    wconv_k<<<66, 256, 0, stream>>>((const unsigned short*)x, (const unsigned int*)ei,
                                    Wm, Wu, bm, bu, ga, be, WfMT, WfUT, prm, flg);

    // fused: proj(Ps) + proj(Pt) + bhist in one dispatch (independent block ranges)
    pj_k<<<2304, 256, 0, stream>>>(flg, x, WfMT, prm, Ps, Pt, ei, BktCnt);

    bscan_k<<<1, 1024, 0, stream>>>(BktCnt, BktOff, BktCur);
    bfill_k<<<128, 256, 0, stream>>>(flg, ei, BktCur, BktE);
    tsort_k<<<NBUCK, 256, 0, stream>>>(BktOff, BktE, CsrSrc, Row);

    // chunk->target table (one search per chunk; BktE is dead, reuse as ChunkT)
    cstart_k<<<(NCHUNK + 256) / 256, 256, 0, stream>>>(Row, ChunkT);

    agg_k<<<(NCHUNK + 3) / 4, 256, 0, stream>>>(Ps, Pt, Row, CsrSrc, ChunkT, Msg);

    // t1 = x@Wu_x^T + b_upd (fp32 row-major), overwrites Ps/Pt (now dead)
    mm_k<<<1024, 256, 0, stream>>>(flg, x, WfUT, prm + 64, t1, 1);

    u2_k<<<1024, 256, 0, stream>>>(flg, x, Msg, t1, WfUT + 4096, prm, d_out);
}

// Round 19
// 302.249 us; speedup vs baseline: 10.8422x; 1.0643x over previous
//
#include <hip/hip_runtime.h>
#include <hip/hip_bf16.h>
#include <stdint.h>

#define NNODES 100000
#define DF 64
#define NEDGES 1600000
#define ND (NNODES * DF)     // 6,400,000
#define BKT 100              // targets per bucket
#define NBUCK 1000           // BKT*NBUCK == NNODES
#define CHUNK 128            // edges per wave in agg_k
#define NCHUNK (NEDGES / CHUNK)   // 12500
#define NPW 25               // nodes per wave in mm/u2 (4096 waves * 25 >= NNODES)
#define NHB 256              // histogram blocks (pj bhist branch / bfill partition)

// ---------- helpers ----------
static __device__ __forceinline__ float bf2f(unsigned short u) {
    union { uint32_t i; float f; } c; c.i = ((uint32_t)u) << 16; return c.f;
}
static __device__ __forceinline__ unsigned short f2bf(float f) {
    union { __hip_bfloat16 b; unsigned short u; } c; c.b = __float2bfloat16(f); return c.u;
}
static __device__ __forceinline__ void unpack2(uint32_t u, float& lo, float& hi) {
    union { uint32_t i; float f; } a, b;
    a.i = u << 16; b.i = u & 0xFFFF0000u;
    lo = a.f; hi = b.f;
}

// ---------- weight canonicalization + dtype detection + BktCnt zeroing ----------
// R19: threads with i<NBUCK also zero BktCnt (drops the hipMemsetAsync dispatch;
// wconv runs strictly before pj_k's histogram atomics).
__global__ void wconv_k(const unsigned short* __restrict__ x,
                        const unsigned int* __restrict__ eiu,
                        const void* __restrict__ Wm, const void* __restrict__ Wu,
                        const void* __restrict__ bm, const void* __restrict__ bu,
                        const void* __restrict__ ga, const void* __restrict__ be,
                        float* __restrict__ WfMT, float* __restrict__ WfUT,
                        float* __restrict__ prm, int* __restrict__ flags,
                        int* __restrict__ BktCnt) {
    __shared__ int cnt_sane, cnt_odd_nz;
    if (threadIdx.x == 0) { cnt_sane = 0; cnt_odd_nz = 0; }
    __syncthreads();
    {
        unsigned short s = x[threadIdx.x * 2];
        unsigned short m = s & 0x7FFF;
        if (m < 0x0080 || (m >= 0x3000 && m <= 0x4200)) atomicAdd(&cnt_sane, 1);
        if (threadIdx.x < 64) {
            if (eiu[threadIdx.x * 2 + 1] != 0u) atomicAdd(&cnt_odd_nz, 1);
        }
    }
    __syncthreads();
    const int bf = (cnt_sane >= 192) ? 1 : 0;
    if (blockIdx.x == 0 && threadIdx.x == 0) {
        flags[0] = bf;
        flags[1] = (cnt_odd_nz == 0) ? 1 : 0;
    }
    int i = blockIdx.x * 256 + threadIdx.x;
    if (i < NBUCK) BktCnt[i] = 0;
    if (i < 16384) {
        const void* src = (i < 8192) ? Wm : Wu;
        float* dst = (i < 8192) ? WfMT : WfUT;
        int ii = i & 8191, j = ii >> 6, k = ii & 63;
        int si = (j & 63) * 128 + ((j >> 6) ? 64 : 0) + k;
        float v = bf ? bf2f(((const unsigned short*)src)[si]) : ((const float*)src)[si];
        dst[(j >> 6) * 4096 + k * 64 + (j & 63)] = v;
    } else if (i < 16384 + 320) {
        int t = i - 16384, which = t >> 6, k = t & 63;
        if (which == 4) { prm[t] = 0.f; }
        else {
            const void* p = (which == 0) ? bm : (which == 1) ? bu : (which == 2) ? ga : be;
            prm[t] = bf ? bf2f(((const unsigned short*)p)[k]) : ((const float*)p)[k];
        }
    }
}

// ---------- fused phase-1: proj(Ps) + proj(Pt) + bhist (R18-proven) ----------
// R19 addition: the bhist branch also SAVES its per-block histogram to HBlk
// (aliased onto CsrSrc, dead until tsort) so bfill can skip its first edge pass.
__global__ __launch_bounds__(256, 1) void pj_k(const int* __restrict__ flags,
                                               const void* __restrict__ xv,
                                               const float* __restrict__ WfMT,
                                               const float* __restrict__ prm,
                                               unsigned short* __restrict__ Ps,
                                               unsigned short* __restrict__ Pt,
                                               const int* __restrict__ ei,
                                               int* __restrict__ BktCnt,
                                               int* __restrict__ HBlk) {
    const int blk = blockIdx.x;
    if (blk < 2048) {
        const int lane = threadIdx.x & 63;
        const int wib = __builtin_amdgcn_readfirstlane(threadIdx.x >> 6);
        const int bf = flags[0];
        const int mtx = (blk >= 1024);           // block-uniform
        const float* WT = WfMT + (mtx ? 4096 : 0);

        float w[64];
        #pragma unroll
        for (int k = 0; k < 64; ++k) w[k] = WT[k * 64 + lane];
        const float bs = mtx ? prm[lane] : 0.f;
        unsigned short* outp = mtx ? Pt : Ps;

        const int wv = (blk & 1023) * 4 + wib;
        const int n0 = wv * NPW;
        if (n0 >= NNODES) return;
        const int n1 = (n0 + NPW < NNODES) ? n0 + NPW : NNODES;
        for (int n = n0; n < n1; ++n) {
            float a0 = 0.f, a1 = 0.f, a2 = 0.f, a3 = 0.f;
            if (bf) {
                const uint4* xr = (const uint4*)((const unsigned short*)xv + (size_t)n * DF);
                #pragma unroll
                for (int q = 0; q < 8; ++q) {
                    uint4 v = xr[q];
                    float x0,x1,x2,x3,x4,x5,x6,x7;
                    unpack2(v.x, x0, x1); unpack2(v.y, x2, x3);
                    unpack2(v.z, x4, x5); unpack2(v.w, x6, x7);
                    a0 = fmaf(x0, w[8*q+0], a0); a1 = fmaf(x1, w[8*q+1], a1);
                    a2 = fmaf(x2, w[8*q+2], a2); a3 = fmaf(x3, w[8*q+3], a3);
                    a0 = fmaf(x4, w[8*q+4], a0); a1 = fmaf(x5, w[8*q+5], a1);
                    a2 = fmaf(x6, w[8*q+6], a2); a3 = fmaf(x7, w[8*q+7], a3);
                }
            } else {
                const float4* xr = (const float4*)((const float*)xv + (size_t)n * DF);
                #pragma unroll
                for (int q = 0; q < 16; ++q) {
                    float4 v = xr[q];
                    a0 = fmaf(v.x, w[4*q+0], a0); a1 = fmaf(v.y, w[4*q+1], a1);
                    a2 = fmaf(v.z, w[4*q+2], a2); a3 = fmaf(v.w, w[4*q+3], a3);
                }
            }
            outp[(size_t)n * DF + lane] = f2bf((a0 + a1) + (a2 + a3) + bs);
        }
    } else {
        // ---- bhist branch: NHB blocks, LDS pre-aggregated; saves per-block h ----
        __shared__ int h[NBUCK];
        const int i64 = flags[1];
        const int hb = blk - 2048;
        for (int i = threadIdx.x; i < NBUCK; i += 256) h[i] = 0;
        __syncthreads();
        for (int e = hb * 256 + threadIdx.x; e < NEDGES; e += NHB * 256) {
            int tgt = i64 ? ei[4*e + 2] : ei[2*e + 1];
            if ((unsigned)tgt < NNODES) atomicAdd(&h[tgt / BKT], 1);
        }
        __syncthreads();
        for (int b = threadIdx.x; b < NBUCK; b += 256) {
            int v = h[b];
            HBlk[hb * NBUCK + b] = v;
            if (v) atomicAdd(BktCnt + b, v);
        }
    }
}

// ---------- scan of 1000 bucket counts (unchanged) ----------
__global__ __launch_bounds__(1024) void bscan_k(const int* __restrict__ BktCnt,
                                                int* __restrict__ BktOff,
                                                int* __restrict__ BktCur) {
    __shared__ int lds[1024];
    int t = threadIdx.x;
    int c = (t < NBUCK) ? BktCnt[t] : 0;
    lds[t] = c;
    __syncthreads();
    for (int off = 1; off < 1024; off <<= 1) {
        int add = (t >= off) ? lds[t - off] : 0;
        __syncthreads();
        lds[t] += add;
        __syncthreads();
    }
    if (t < NBUCK) {
        int ex = lds[t] - c;
        BktOff[t] = ex;
        BktCur[t] = ex;
    }
    if (t == NBUCK - 1) BktOff[NBUCK] = lds[t];
}

// ---------- bucket fill: SINGLE edge pass (histogram pre-saved in HBlk) ----------
// R19: 256 blocks with the SAME edge partition as pj_k's bhist branch; the
// reservation histogram is loaded from HBlk instead of re-scanning the edges.
__global__ __launch_bounds__(256) void bfill_k(const int* __restrict__ flags,
                                               const int* __restrict__ ei,
                                               const int* __restrict__ HBlk,
                                               int* __restrict__ BktCur,
                                               int* __restrict__ BktE) {
    __shared__ int h2[NBUCK], basee[NBUCK];
    const int i64 = flags[1];
    const int blk = blockIdx.x;
    for (int i = threadIdx.x; i < NBUCK; i += 256) h2[i] = 0;
    __syncthreads();
    for (int b = threadIdx.x; b < NBUCK; b += 256) {
        int hv = HBlk[blk * NBUCK + b];
        basee[b] = hv ? atomicAdd(BktCur + b, hv) : 0;
    }
    __syncthreads();
    for (int e = blk * 256 + threadIdx.x; e < NEDGES; e += NHB * 256) {
        int src, tgt;
        if (i64) { src = ei[4*e]; tgt = ei[4*e + 2]; }
        else     { src = ei[2*e]; tgt = ei[2*e + 1]; }
        if ((unsigned)tgt >= NNODES) continue;
        int b = tgt / BKT;
        int tl = tgt - b * BKT;
        int r = atomicAdd(&h2[b], 1);
        BktE[basee[b] + r] = (tl << 24) | (src & 0xFFFFFF);
    }
}

// ---------- per-bucket counting sort by target -> CsrSrc + Row (unchanged) ----------
// CsrSrc entries are pre-clamped and PRE-MULTIPLIED by DF.
__global__ __launch_bounds__(256) void tsort_k(const int* __restrict__ BktOff,
                                               const int* __restrict__ BktE,
                                               int* __restrict__ CsrSrc,
                                               int* __restrict__ Row) {
    __shared__ int oc[128], excl[128], cur[128];
    const int tid = threadIdx.x;
    const int b = blockIdx.x;
    const int s = BktOff[b], e = BktOff[b + 1];
    const int n = e - s;
    if (tid < 128) { oc[tid] = 0; }
    __syncthreads();
    for (int i = tid; i < n; i += 256)
        atomicAdd(&oc[((unsigned)BktE[s + i]) >> 24], 1);
    __syncthreads();
    if (tid < 128) excl[tid] = (tid > 0) ? oc[tid - 1] : 0;
    __syncthreads();
    for (int off = 1; off < 128; off <<= 1) {
        int add = (tid >= off && tid < 128) ? excl[tid - off] : 0;
        __syncthreads();
        if (tid < 128) excl[tid] += add;
        __syncthreads();
    }
    if (tid < BKT) {
        Row[b * BKT + tid] = s + excl[tid];
        cur[tid] = excl[tid];
    }
    if (b == 0 && tid == 0) Row[NNODES] = NEDGES;
    __syncthreads();
    for (int i = tid; i < n; i += 256) {
        int v = BktE[s + i];
        int tl = ((unsigned)v) >> 24;
        int p = atomicAdd(&cur[tl], 1);
        int sv = v & 0xFFFFFF;
        if (sv >= NNODES) sv = 0;
        CsrSrc[s + p] = sv << 6;   // * DF
    }
}

// ---------- aggregation: lane = dim, masked-16 gather, INLINE chunk searches ----------
// R19: binary searches back in-kernel (R4/R15-audited) — drops the cstart launch.
__global__ __launch_bounds__(256) void agg_k(const unsigned short* __restrict__ Ps,
                                             const unsigned short* __restrict__ Pt,
                                             const int* __restrict__ Row,
                                             const int* __restrict__ CsrSrc,
                                             unsigned short* __restrict__ Msg) {
    const int lane = threadIdx.x & 63;
    const int wib = __builtin_amdgcn_readfirstlane(threadIdx.x >> 6);
    const int w = blockIdx.x * 4 + wib;
    if (w >= NCHUNK) return;

    const int eA = w * CHUNK;
    int lo = 0, hi = NNODES + 1;
    while (lo < hi) { int mid = (lo + hi) >> 1; if (Row[mid] >= eA) hi = mid; else lo = mid + 1; }
    const int t_lo = lo;
    int t_hi;
    if (w == NCHUNK - 1) t_hi = NNODES;
    else {
        const int hiB = eA + CHUNK;
        lo = t_lo; hi = NNODES + 1;
        while (lo < hi) { int mid = (lo + hi) >> 1; if (Row[mid] >= hiB) hi = mid; else lo = mid + 1; }
        t_hi = (lo > NNODES) ? NNODES : lo;
    }
    if (t_lo >= t_hi) return;

    int segS = Row[t_lo];
    for (int t = t_lo; t < t_hi; ++t) {
        const int segE = Row[t + 1];
        const int deg = segE - segS;
        float ptv = bf2f(Pt[(size_t)t * DF + lane]);
        float pa0 = 0.f, pa1 = 0.f, pa2 = 0.f, pa3 = 0.f;
        for (int i = segS; i < segE; i += 16) {
            #pragma unroll
            for (int j = 0; j < 16; ++j) {
                const int idx = i + j;
                const int ok = idx < segE;
                const int sv = CsrSrc[ok ? idx : segS];   // pre-clamped, pre-*DF
                float p = bf2f(Ps[(size_t)(unsigned)sv + lane]);
                float v = ok ? fmaxf(p + ptv, 0.f) : 0.f;
                if ((j & 3) == 0)      pa0 += v;
                else if ((j & 3) == 1) pa1 += v;
                else if ((j & 3) == 2) pa2 += v;
                else                   pa3 += v;
            }
        }
        float macc = (pa0 + pa1) + (pa2 + pa3);
        float mval = (deg > 0) ? (macc / (float)deg) : 0.f;
        Msg[(size_t)t * DF + lane] = f2bf(mval);
        segS = segE;
    }
}

// ---------- generic row-matmul (used for t1) ----------
__global__ __launch_bounds__(256, 1) void mm_k(const int* __restrict__ flags,
                                               const void* __restrict__ xv,
                                               const float* __restrict__ WT,
                                               const float* __restrict__ bias,
                                               void* __restrict__ outv,
                                               int of) {
    const int lane = threadIdx.x & 63;
    const int wib = __builtin_amdgcn_readfirstlane(threadIdx.x >> 6);
    const int bf = flags[0];

    float w[64];
    #pragma unroll
    for (int k = 0; k < 64; ++k) w[k] = WT[k * 64 + lane];
    const float bs = bias[lane];

    const int wv = blockIdx.x * 4 + wib;
    const int n0 = wv * NPW;
    if (n0 >= NNODES) return;
    const int n1 = (n0 + NPW < NNODES) ? n0 + NPW : NNODES;
    for (int n = n0; n < n1; ++n) {
        float a0 = 0.f, a1 = 0.f, a2 = 0.f, a3 = 0.f;
        if (bf) {
            const uint4* xr = (const uint4*)((const unsigned short*)xv + (size_t)n * DF);
            #pragma unroll
            for (int q = 0; q < 8; ++q) {
                uint4 v = xr[q];
                float x0,x1,x2,x3,x4,x5,x6,x7;
                unpack2(v.x, x0, x1); unpack2(v.y, x2, x3);
                unpack2(v.z, x4, x5); unpack2(v.w, x6, x7);
                a0 = fmaf(x0, w[8*q+0], a0); a1 = fmaf(x1, w[8*q+1], a1);
                a2 = fmaf(x2, w[8*q+2], a2); a3 = fmaf(x3, w[8*q+3], a3);
                a0 = fmaf(x4, w[8*q+4], a0); a1 = fmaf(x5, w[8*q+5], a1);
                a2 = fmaf(x6, w[8*q+6], a2); a3 = fmaf(x7, w[8*q+7], a3);
            }
        } else {
            const float4* xr = (const float4*)((const float*)xv + (size_t)n * DF);
            #pragma unroll
            for (int q = 0; q < 16; ++q) {
                float4 v = xr[q];
                a0 = fmaf(v.x, w[4*q+0], a0); a1 = fmaf(v.y, w[4*q+1], a1);
                a2 = fmaf(v.z, w[4*q+2], a2); a3 = fmaf(v.w, w[4*q+3], a3);
            }
        }
        float r = (a0 + a1) + (a2 + a3) + bs;
        size_t gi = (size_t)n * DF + lane;
        if (of) ((float*)outv)[gi] = r;
        else    ((unsigned short*)outv)[gi] = f2bf(r);
    }
}

// ---------- u2: r = relu(t1 + Msg@Wu_m^T) + x ; LayerNorm ; out (unchanged) ----------
__global__ __launch_bounds__(256, 1) void u2_k(const int* __restrict__ flags,
                                               const void* __restrict__ xv,
                                               const unsigned short* __restrict__ Msg,
                                               const float* __restrict__ t1,
                                               const float* __restrict__ WT,
                                               const float* __restrict__ prm,
                                               void* __restrict__ outv) {
    const int lane = threadIdx.x & 63;
    const int wib = __builtin_amdgcn_readfirstlane(threadIdx.x >> 6);
    const int bf = flags[0];

    float w[64];
    #pragma unroll
    for (int k = 0; k < 64; ++k) w[k] = WT[k * 64 + lane];
    const float ga = prm[128 + lane];
    const float be = prm[192 + lane];

    const unsigned short* x16 = (const unsigned short*)xv;
    const float* xf = (const float*)xv;

    const int wv = blockIdx.x * 4 + wib;
    const int n0 = wv * NPW;
    if (n0 >= NNODES) return;
    const int n1 = (n0 + NPW < NNODES) ? n0 + NPW : NNODES;
    for (int n = n0; n < n1; ++n) {
        float b0 = 0.f, b1 = 0.f, b2 = 0.f, b3 = 0.f;
        const uint4* mw = (const uint4*)(Msg + (size_t)n * DF);
        #pragma unroll
        for (int q = 0; q < 8; ++q) {
            uint4 v = mw[q];
            float m0,m1,m2,m3,m4,m5,m6,m7;
            unpack2(v.x, m0, m1); unpack2(v.y, m2, m3);
            unpack2(v.z, m4, m5); unpack2(v.w, m6, m7);
            b0 = fmaf(m0, w[8*q+0], b0); b1 = fmaf(m1, w[8*q+1], b1);
            b2 = fmaf(m2, w[8*q+2], b2); b3 = fmaf(m3, w[8*q+3], b3);
            b0 = fmaf(m4, w[8*q+4], b0); b1 = fmaf(m5, w[8*q+5], b1);
            b2 = fmaf(m6, w[8*q+6], b2); b3 = fmaf(m7, w[8*q+7], b3);
        }
        size_t gi = (size_t)n * DF + lane;
        float t  = t1[gi];
        float xl = bf ? bf2f(x16[gi]) : xf[gi];
        float u = fmaxf((b0 + b1) + (b2 + b3) + t, 0.f);
        float r = u + xl;

        float s = r, s2 = r * r;
        #pragma unroll
        for (int m = 1; m < 64; m <<= 1) {
            s  += __shfl_xor(s, m, 64);
            s2 += __shfl_xor(s2, m, 64);
        }
        float mu  = s * (1.0f / 64.0f);
        float var = fmaxf(s2 * (1.0f / 64.0f) - mu * mu, 0.f);
        float o = (r - mu) * rsqrtf(var + 1e-5f) * ga + be;

        if (bf) ((__hip_bfloat16*)outv)[gi] = __float2bfloat16(o);
        else    ((float*)outv)[gi] = o;
    }
}

extern "C" void kernel_launch(void* const* d_in, const int* in_sizes, int n_in,
                              void* d_out, int out_size, void* d_ws, size_t ws_size,
                              hipStream_t stream) {
    const void* x  = d_in[0];
    const int*  ei = (const int*)d_in[1];
    const void* Wm = d_in[2];
    const void* bm = d_in[3];
    const void* Wu = d_in[4];
    const void* bu = d_in[5];
    const void* ga = d_in[6];
    const void* be = d_in[7];

    char* ws = (char*)d_ws;
    size_t off = 0;
    unsigned short* Ps  = (unsigned short*)(ws + off); off += (size_t)ND * 2;   // 12.8 MB
    unsigned short* Pt  = (unsigned short*)(ws + off); off += (size_t)ND * 2;   // 12.8 MB
    unsigned short* Msg = (unsigned short*)(ws + off); off += (size_t)ND * 2;   // 12.8 MB
    int*   BktE   = (int*)(ws + off); off += (size_t)NEDGES * 4;                // 6.4 MB
    int*   CsrSrc = (int*)(ws + off); off += (size_t)NEDGES * 4;                // 6.4 MB
    int*   Row    = (int*)(ws + off); off += (size_t)(NNODES + 1) * 4;
    int*   BktCnt = (int*)(ws + off); off += NBUCK * 4;                         // zeroed by wconv_k
    int*   BktOff = (int*)(ws + off); off += (NBUCK + 1) * 4;
    int*   BktCur = (int*)(ws + off); off += NBUCK * 4;
    int*   flg    = (int*)(ws + off); off += 16;
    float* WfMT   = (float*)(ws + off); off += 8192 * 4;
    float* WfUT   = (float*)(ws + off); off += 8192 * 4;
    float* prm    = (float*)(ws + off); off += 320 * 4;

    // t1 (fp32, 25.6 MB) reuses Ps+Pt region — valid because mm_k(t1) runs AFTER agg_k.
    float* t1 = (float*)Ps;
    // HBlk (256*1000 ints = 1 MB) aliases CsrSrc — written by pj_k, read by bfill_k,
    // then CsrSrc is (re)written by tsort_k. Sequential dispatches => safe.
    int* HBlk = CsrSrc;

    // wconv: dtype detection + weight transpose + BktCnt zeroing (no memset dispatch)
    wconv_k<<<66, 256, 0, stream>>>((const unsigned short*)x, (const unsigned int*)ei,
                                    Wm, Wu, bm, bu, ga, be, WfMT, WfUT, prm, flg, BktCnt);

    // fused: proj(Ps) + proj(Pt) + bhist (saves per-block hist to HBlk)
    pj_k<<<2048 + NHB, 256, 0, stream>>>(flg, x, WfMT, prm, Ps, Pt, ei, BktCnt, HBlk);

    bscan_k<<<1, 1024, 0, stream>>>(BktCnt, BktOff, BktCur);

    // single-pass bucket fill (reservation histogram from HBlk)
    bfill_k<<<NHB, 256, 0, stream>>>(flg, ei, HBlk, BktCur, BktE);

    tsort_k<<<NBUCK, 256, 0, stream>>>(BktOff, BktE, CsrSrc, Row);

    // agg with inline chunk searches (cstart launch dropped)
    agg_k<<<(NCHUNK + 3) / 4, 256, 0, stream>>>(Ps, Pt, Row, CsrSrc, Msg);

    // t1 = x@Wu_x^T + b_upd (fp32 row-major), overwrites Ps/Pt (now dead)
    mm_k<<<1024, 256, 0, stream>>>(flg, x, WfUT, prm + 64, t1, 1);

    u2_k<<<1024, 256, 0, stream>>>(flg, x, Msg, t1, WfUT + 4096, prm, d_out);
}